// Round 5
// baseline (302.531 us; speedup 1.0000x reference)
//
#include <hip/hip_runtime.h>

// ---------------- problem constants ----------------
#define CDIM 1152
#define NDIS 30
#define NVOX (64*64*64)        // 262144 voxels
#define NT   128               // voxels per block
#define NBLK2 (NVOX/NT)        // 2048 blocks
#define KSTEPS (CDIM/32)       // 36 K-steps of 32 channels

// ---------------- workspace layout (float offsets) ----------------
// A-fragments: [t(36)][mt(4)][p(2)][lane(64)][e(8)] shorts = 147456 shorts = 73728 floats
#define AF_FLOATS 73728
#define PM_OFF AF_FLOATS                    // [30][2048] per-block max of s
#define PD_OFF (PM_OFF + NDIS*NBLK2)        // [30][2048] per-block sum e
#define PN_OFF (PD_OFF + NDIS*NBLK2)        // [30][2048] per-block sum e*h

typedef float f32x4 __attribute__((ext_vector_type(4)));
typedef short bf16x8 __attribute__((ext_vector_type(8)));

// RTNE f32 -> bf16 (bits), and back
__device__ inline short f2bf(float f) {
    unsigned u = __float_as_uint(f);
    unsigned r = (u + 0x7FFFu + ((u >> 16) & 1u)) >> 16;
    return (short)r;
}
__device__ inline float bf2f(short h) {
    return __uint_as_float(((unsigned)(unsigned short)h) << 16);
}
__device__ inline float inv_tau(float t) {
    float sig = 1.f / (1.f + expf(-t));
    return 1.f / (0.2f + 1.8f * sig);
}

// K0: precompute per-lane A-fragments (weights, bf16 hi/lo split).
// A-row m = lane&15 (m: 0..29 score_w, 30..59 head_w, 60..63 zero),
// k-slot map: k = 8*(lane>>4) + e  (same map used packing B -> consistency).
__global__ void k_prep(const float* __restrict__ score_w,
                       const float* __restrict__ head_w,
                       short* __restrict__ afrag) {
    int idx = blockIdx.x * 256 + threadIdx.x;      // 147456 total
    int e  = idx & 7;
    int l  = (idx >> 3) & 63;
    int p  = (idx >> 9) & 1;
    int mt = (idx >> 10) & 3;
    int t  = idx >> 12;
    if (t >= KSTEPS) return;
    int m = mt * 16 + (l & 15);
    int k = t * 32 + 8 * (l >> 4) + e;
    float w = 0.f;
    if (m < NDIS)          w = score_w[m * CDIM + k];
    else if (m < 2 * NDIS) w = head_w[(m - NDIS) * CDIM + k];
    short hi = f2bf(w);
    afrag[idx] = p ? f2bf(w - bf2f(hi)) : hi;
}

// Load step TT's 16 B-values (this wave's own 32x32 sub-tile slice) to regs.
// Lanes i16=0..15 read 64B contiguous; nt=0/1 complete each 128B line.
#define LOADB(TT, BD)                                                          \
    {                                                                          \
        const float* bp = bstep + (size_t)(TT) * (32 * (size_t)NVOX);          \
        _Pragma("unroll") for (int e = 0; e < 8; e++) {                        \
            BD[e]     = bp[(size_t)e * NVOX];                                  \
            BD[8 + e] = bp[(size_t)e * NVOX + 16];                             \
        }                                                                      \
    }

// One K-step. Issue order matters for in-order vmcnt retirement:
//   A(T) loads -> sched_barrier -> B(T+1) prefetch -> convert B(T) -> MFMA.
// Conversion's wait drains only through B(T) (leaves A(T)+B(T+1) in flight);
// MFMA's wait drains through A(T) (leaves the 16 B(T+1) HBM loads in flight).
#define BODY(T, BC, BN)                                                        \
    {                                                                          \
        bf16x8 ah[4], al[4];                                                   \
        _Pragma("unroll") for (int mt = 0; mt < 4; mt++) {                     \
            ah[mt] = afp[(size_t)((T) * 8 + mt * 2 + 0) * 64 + lane];          \
            al[mt] = afp[(size_t)((T) * 8 + mt * 2 + 1) * 64 + lane];          \
        }                                                                      \
        __builtin_amdgcn_sched_barrier(0);                                     \
        int tn = ((T) + 1 < KSTEPS) ? (T) + 1 : KSTEPS - 1;                    \
        LOADB(tn, BN);                                                         \
        bf16x8 bh[2], bl[2];                                                   \
        _Pragma("unroll") for (int nt = 0; nt < 2; nt++)                       \
            _Pragma("unroll") for (int e = 0; e < 8; e++) {                    \
                float f = BC[nt * 8 + e];                                      \
                short hs = f2bf(f);                                            \
                bh[nt][e] = hs;                                                \
                float lf = f - bf2f(hs);                                       \
                bl[nt][e] = (short)(__float_as_uint(lf) >> 16);                \
            }                                                                  \
        _Pragma("unroll") for (int mt = 0; mt < 4; mt++)                       \
            _Pragma("unroll") for (int nt = 0; nt < 2; nt++) {                 \
                acc[mt][nt] = __builtin_amdgcn_mfma_f32_16x16x32_bf16(ah[mt], bh[nt], acc[mt][nt], 0, 0, 0); \
                acc[mt][nt] = __builtin_amdgcn_mfma_f32_16x16x32_bf16(ah[mt], bl[nt], acc[mt][nt], 0, 0, 0); \
                acc[mt][nt] = __builtin_amdgcn_mfma_f32_16x16x32_bf16(al[mt], bh[nt], acc[mt][nt], 0, 0, 0); \
            }                                                                  \
    }

// K1 (hot): register-staged bf16-split MFMA projection, no LDS staging,
// no K-loop barriers. Fused per-block softmax partials in the epilogue.
__global__ __launch_bounds__(256) void k_mfma(const float* __restrict__ activ,
                                              const short* __restrict__ afrag,
                                              const float* __restrict__ temp_logit,
                                              float* __restrict__ pm,
                                              float* __restrict__ pd,
                                              float* __restrict__ pn) {
    __shared__ float ep[64][NT];              // 32 KB epilogue tile
    __shared__ float redm[32][8], rede[32][8], redh[32][8];

    const int tid  = threadIdx.x;
    const int lane = tid & 63;
    const int w    = tid >> 6;                // wave 0..3
    const int a    = lane >> 4;               // k-group 0..3
    const int i16  = lane & 15;
    const int nb   = blockIdx.x * NT;

    const bf16x8* afp = (const bf16x8*)afrag;
    // per-lane base: row block 8a, this wave's 32-col slice, lane's col i16
    const float* bstep = activ + (size_t)(8 * a) * NVOX + nb + w * 32 + i16;

    f32x4 acc[4][2];
#pragma unroll
    for (int mt = 0; mt < 4; mt++)
#pragma unroll
        for (int nt = 0; nt < 2; nt++) acc[mt][nt] = (f32x4)0.f;

    float B0[16], B1[16];
    LOADB(0, B0);

#pragma unroll 1
    for (int t = 0; t < KSTEPS; t += 2) {
        BODY(t,     B0, B1);
        BODY(t + 1, B1, B0);
    }

    // ---- epilogue: dump D[64][128] to LDS, then block softmax partials ----
#pragma unroll
    for (int mt = 0; mt < 4; mt++)
#pragma unroll
        for (int nt = 0; nt < 2; nt++)
#pragma unroll
            for (int r = 0; r < 4; r++) {
                int m = mt * 16 + a * 4 + r;  // verified C/D map: row=(lane>>4)*4+reg
                int n = w * 32 + nt * 16 + i16;
                ep[m][n] = acc[mt][nt][r];
            }
    __syncthreads();

    const int d  = tid >> 3;                  // 0..31 (30 used)
    const int j8 = tid & 7;                   // 8 threads per disease
    if (d < NDIS) {
        float mx = -3.4e38f;
        for (int i = 0; i < 16; i++) mx = fmaxf(mx, ep[d][j8 * 16 + i]);
        redm[d][j8] = mx;
    }
    __syncthreads();
    if (d < NDIS) {
        float mb = redm[d][0];
        for (int j = 1; j < 8; j++) mb = fmaxf(mb, redm[d][j]);
        float it = inv_tau(temp_logit[d]);
        float se = 0.f, sh = 0.f;
        for (int i = 0; i < 16; i++) {
            float e = expf((ep[d][j8 * 16 + i] - mb) * it);
            se += e;
            sh += e * ep[d + NDIS][j8 * 16 + i];
        }
        rede[d][j8] = se;
        redh[d][j8] = sh;
    }
    __syncthreads();
    if (tid < NDIS) {
        float mb = redm[tid][0];
        for (int j = 1; j < 8; j++) mb = fmaxf(mb, redm[tid][j]);
        float se = 0.f, sh = 0.f;
        for (int j = 0; j < 8; j++) { se += rede[tid][j]; sh += redh[tid][j]; }
        pm[tid * NBLK2 + blockIdx.x] = mb;
        pd[tid * NBLK2 + blockIdx.x] = se;
        pn[tid * NBLK2 + blockIdx.x] = sh;
    }
}

// K2: merge 2048 per-block partials per disease with max-rescaling.
__global__ __launch_bounds__(256) void k_final(const float* __restrict__ pm,
                                               const float* __restrict__ pd,
                                               const float* __restrict__ pn,
                                               const float* __restrict__ temp_logit,
                                               const float* __restrict__ head_b,
                                               float* __restrict__ out) {
    const int d = blockIdx.x, tid = threadIdx.x;
    const int lane = tid & 63, wid = tid >> 6;
    __shared__ float sm[4], sd[4], sn[4];
    const float* bm = pm + d * NBLK2;
    const float* bd = pd + d * NBLK2;
    const float* bn = pn + d * NBLK2;

    float m[8], e[8], h[8];
#pragma unroll
    for (int i = 0; i < 8; i++) {
        int ix = tid + i * 256;
        m[i] = bm[ix]; e[i] = bd[ix]; h[i] = bn[ix];
    }
    float mx = m[0];
#pragma unroll
    for (int i = 1; i < 8; i++) mx = fmaxf(mx, m[i]);
#pragma unroll
    for (int off = 32; off > 0; off >>= 1) mx = fmaxf(mx, __shfl_xor(mx, off));
    if (lane == 0) sm[wid] = mx;
    __syncthreads();
    float M = fmaxf(fmaxf(sm[0], sm[1]), fmaxf(sm[2], sm[3]));

    float it = inv_tau(temp_logit[d]);
    float den = 0.f, num = 0.f;
#pragma unroll
    for (int i = 0; i < 8; i++) {
        float sc = expf((m[i] - M) * it);
        den += e[i] * sc;
        num += h[i] * sc;
    }
#pragma unroll
    for (int off = 32; off > 0; off >>= 1) {
        den += __shfl_xor(den, off);
        num += __shfl_xor(num, off);
    }
    if (lane == 0) { sd[wid] = den; sn[wid] = num; }
    __syncthreads();
    if (tid == 0) {
        float D = (sd[0] + sd[1]) + (sd[2] + sd[3]);
        float N = (sn[0] + sn[1]) + (sn[2] + sn[3]);
        float o = N / fmaxf(D, 1e-12f) + head_b[d];
        if (o != o) o = 0.f;
        out[d] = o;
    }
}

extern "C" void kernel_launch(void* const* d_in, const int* in_sizes, int n_in,
                              void* d_out, int out_size, void* d_ws, size_t ws_size,
                              hipStream_t stream) {
    const float* activ      = (const float*)d_in[0];
    const float* score_w    = (const float*)d_in[1];
    // d_in[2] = score_b — cancels exactly in the stable softmax, unused
    const float* head_w     = (const float*)d_in[3];
    const float* head_b     = (const float*)d_in[4];
    const float* temp_logit = (const float*)d_in[5];
    float* ws  = (float*)d_ws;
    float* out = (float*)d_out;

    short* afrag = (short*)ws;
    k_prep <<<576,   256, 0, stream>>>(score_w, head_w, afrag);
    k_mfma <<<NBLK2, 256, 0, stream>>>(activ, afrag, temp_logit,
                                       ws + PM_OFF, ws + PD_OFF, ws + PN_OFF);
    k_final<<<NDIS,  256, 0, stream>>>(ws + PM_OFF, ws + PD_OFF, ws + PN_OFF,
                                       temp_logit, head_b, out);
}

// Round 6
// 255.687 us; speedup vs baseline: 1.1832x; 1.1832x over previous
//
#include <hip/hip_runtime.h>

// ---------------- problem constants ----------------
#define CDIM 1152
#define NDIS 30
#define NVOX (64*64*64)        // 262144 voxels
#define NT   128               // voxels per block
#define NBLK2 (NVOX/NT)        // 2048 blocks
#define KSTEPS (CDIM/32)       // 36 K-steps of 32 channels

// ---------------- workspace layout (float offsets) ----------------
#define AF_FLOATS 73728
#define PM_OFF AF_FLOATS                    // [30][2048] per-block max of s
#define PD_OFF (PM_OFF + NDIS*NBLK2)        // [30][2048] per-block sum e
#define PN_OFF (PD_OFF + NDIS*NBLK2)        // [30][2048] per-block sum e*h

typedef float f32x4 __attribute__((ext_vector_type(4)));
typedef short bf16x8 __attribute__((ext_vector_type(8)));

__device__ inline short f2bf(float f) {
    unsigned u = __float_as_uint(f);
    unsigned r = (u + 0x7FFFu + ((u >> 16) & 1u)) >> 16;
    return (short)r;
}
__device__ inline float bf2f(short h) {
    return __uint_as_float(((unsigned)(unsigned short)h) << 16);
}
__device__ inline float inv_tau(float t) {
    float sig = 1.f / (1.f + expf(-t));
    return 1.f / (0.2f + 1.8f * sig);
}

// K0: precompute per-lane A-fragments (weights, bf16 hi/lo split).
__global__ void k_prep(const float* __restrict__ score_w,
                       const float* __restrict__ head_w,
                       short* __restrict__ afrag) {
    int idx = blockIdx.x * 256 + threadIdx.x;      // 147456 total
    int e  = idx & 7;
    int l  = (idx >> 3) & 63;
    int p  = (idx >> 9) & 1;
    int mt = (idx >> 10) & 3;
    int t  = idx >> 12;
    if (t >= KSTEPS) return;
    int m = mt * 16 + (l & 15);
    int k = t * 32 + 8 * (l >> 4) + e;
    float w = 0.f;
    if (m < NDIS)          w = score_w[m * CDIM + k];
    else if (m < 2 * NDIS) w = head_w[(m - NDIS) * CDIM + k];
    short hi = f2bf(w);
    afrag[idx] = p ? f2bf(w - bf2f(hi)) : hi;
}

#define SB __builtin_amdgcn_sched_barrier(0)
#define WAITV(N) asm volatile("s_waitcnt vmcnt(" #N ")" ::: "memory")

// A(t) fragments: 8 x 16B coalesced L2 loads
#define LOADA(T, AH, AL)                                                       \
    {                                                                          \
        _Pragma("unroll") for (int mt = 0; mt < 4; mt++) {                     \
            AH[mt] = afp[(size_t)((T) * 8 + mt * 2 + 0) * 64 + lane];          \
            AL[mt] = afp[(size_t)((T) * 8 + mt * 2 + 1) * 64 + lane];          \
        }                                                                      \
    }

// Read B from lds[TP], bf16-split, 24 MFMA (hi*hi + hi*lo + lo*hi)
#define COMPUTE(TP, AH, AL)                                                    \
    {                                                                          \
        bf16x8 bh[2], bl[2];                                                   \
        _Pragma("unroll") for (int nt = 0; nt < 2; nt++) {                     \
            const int col = w * 32 + nt * 16 + i16;                            \
            _Pragma("unroll") for (int e = 0; e < 8; e++) {                    \
                float f = lds[TP][8 * a + e][col];                             \
                short hs = f2bf(f);                                            \
                bh[nt][e] = hs;                                                \
                float lf = f - bf2f(hs);                                       \
                bl[nt][e] = (short)(__float_as_uint(lf) >> 16);                \
            }                                                                  \
        }                                                                      \
        _Pragma("unroll") for (int mt = 0; mt < 4; mt++)                       \
            _Pragma("unroll") for (int nt = 0; nt < 2; nt++) {                 \
                acc[mt][nt] = __builtin_amdgcn_mfma_f32_16x16x32_bf16(AH[mt], bh[nt], acc[mt][nt], 0, 0, 0); \
                acc[mt][nt] = __builtin_amdgcn_mfma_f32_16x16x32_bf16(AH[mt], bl[nt], acc[mt][nt], 0, 0, 0); \
                acc[mt][nt] = __builtin_amdgcn_mfma_f32_16x16x32_bf16(AL[mt], bh[nt], acc[mt][nt], 0, 0, 0); \
            }                                                                  \
    }

// K1 (hot): gld_lds staging, TRIPLE-buffered, staged 2 K-steps ahead,
// raw s_barrier + counted vmcnt (no vmcnt(0) drain in the K-loop).
// Issue-order ledger (per wave, in-order vmcnt retirement):
//   prologue: A0(8) s0(4) s1(4)
//   phase 0 : A1(8) -> wait s0 => vmcnt(12) -> bar -> s2(4) -> compute0[A0]
//   phase t : A(t+1)(8) -> wait s(t) => vmcnt(20) -> bar -> s(t+2)(4) -> compute[A(t)]
//             (compute's auto-wait for A(t) leaves s(t+1), A(t+1), s(t+2) in flight)
//   phase 35: wait s35 => vmcnt(8) -> bar -> compute35[A35]
// Buffer safety: s(t+2) writes buf[(t+2)%3], last read in phase t-1; it is
// issued after barrier(t), which all waves reach only after finishing t-1.
__global__ __launch_bounds__(256, 3) void k_mfma(const float* __restrict__ activ,
                                                 const short* __restrict__ afrag,
                                                 const float* __restrict__ temp_logit,
                                                 float* __restrict__ pm,
                                                 float* __restrict__ pd,
                                                 float* __restrict__ pn) {
    __shared__ float lds[3][32][NT];          // 48 KB, triple-buffered staging
    __shared__ float redm[32][8], rede[32][8], redh[32][8];

    const int tid  = threadIdx.x;
    const int lane = tid & 63;
    const int w    = tid >> 6;                // wave 0..3
    const int a    = lane >> 4;               // k-group 0..3
    const int i16  = lane & 15;
    const int nb   = blockIdx.x * NT;

    const bf16x8* afp = (const bf16x8*)afrag;

    f32x4 acc[4][2];
#pragma unroll
    for (int mt = 0; mt < 4; mt++)
#pragma unroll
        for (int nt = 0; nt < 2; nt++) acc[mt][nt] = (f32x4)0.f;

    // stage K-step t's [32][128] f32 tile into buffer b (4 x gld_lds width 16)
    auto stage = [&](int t, int b) {
#pragma unroll
        for (int q = 0; q < 4; q++) {
            const int row = 8 * w + 2 * q;                       // wave-uniform
            const float* g = activ + (size_t)(t * 32 + row + (lane >> 5)) * NVOX
                           + nb + (lane & 31) * 4;               // per-lane global
            __builtin_amdgcn_global_load_lds(
                (const __attribute__((address_space(1))) unsigned int*)g,
                (__attribute__((address_space(3))) unsigned int*)&lds[b][row][0],
                16, 0, 0);
        }
    };

    bf16x8 ah0[4], al0[4], ah1[4], al1[4];

    // prologue
    LOADA(0, ah0, al0); SB;
    stage(0, 0); stage(1, 1); SB;

    // phase 0 (uses A-set0, buf0; loads A1 -> set1; stages s2)
    LOADA(1, ah1, al1); SB;
    WAITV(12); SB;
    __builtin_amdgcn_s_barrier(); SB;
    stage(2, 2); SB;
    COMPUTE(0, ah0, al0);

#pragma unroll 1
    for (int t = 1; t <= 33; t += 2) {
        // phase t (odd): compute with set1, load A(t+1)->set0, stage t+2
        LOADA(t + 1, ah0, al0); SB;
        WAITV(20); SB;
        __builtin_amdgcn_s_barrier(); SB;
        stage(t + 2, (t + 2) % 3); SB;
        COMPUTE(t % 3, ah1, al1);
        // phase t+1 (even): compute with set0, load A(t+2)->set1, stage t+3
        LOADA(t + 2, ah1, al1); SB;
        WAITV(20); SB;
        __builtin_amdgcn_s_barrier(); SB;
        if (t + 3 < KSTEPS) { stage(t + 3, (t + 3) % 3); }
        SB;
        COMPUTE((t + 1) % 3, ah0, al0);
    }

    // phase 35 (uses set1, buf 35%3=2)
    WAITV(8); SB;
    __builtin_amdgcn_s_barrier(); SB;
    COMPUTE(2, ah1, al1);

    // ---- epilogue: dump D[64][128] to LDS, then block softmax partials ----
    __syncthreads();                          // full drain (everything retired)
    float (*ep)[NT] = (float(*)[NT])lds;      // overlay, 32 KB of the 48
#pragma unroll
    for (int mt = 0; mt < 4; mt++)
#pragma unroll
        for (int nt = 0; nt < 2; nt++)
#pragma unroll
            for (int r = 0; r < 4; r++) {
                int m = mt * 16 + a * 4 + r;  // verified C/D map: row=(lane>>4)*4+reg
                int n = w * 32 + nt * 16 + i16;
                ep[m][n] = acc[mt][nt][r];
            }
    __syncthreads();

    const int d  = tid >> 3;                  // 0..31 (30 used)
    const int j8 = tid & 7;                   // 8 threads per disease
    if (d < NDIS) {
        float mx = -3.4e38f;
        for (int i = 0; i < 16; i++) mx = fmaxf(mx, ep[d][j8 * 16 + i]);
        redm[d][j8] = mx;
    }
    __syncthreads();
    if (d < NDIS) {
        float mb = redm[d][0];
        for (int j = 1; j < 8; j++) mb = fmaxf(mb, redm[d][j]);
        float it = inv_tau(temp_logit[d]);
        float se = 0.f, sh = 0.f;
        for (int i = 0; i < 16; i++) {
            float e = expf((ep[d][j8 * 16 + i] - mb) * it);
            se += e;
            sh += e * ep[d + NDIS][j8 * 16 + i];
        }
        rede[d][j8] = se;
        redh[d][j8] = sh;
    }
    __syncthreads();
    if (tid < NDIS) {
        float mb = redm[tid][0];
        for (int j = 1; j < 8; j++) mb = fmaxf(mb, redm[tid][j]);
        float se = 0.f, sh = 0.f;
        for (int j = 0; j < 8; j++) { se += rede[tid][j]; sh += redh[tid][j]; }
        pm[tid * NBLK2 + blockIdx.x] = mb;
        pd[tid * NBLK2 + blockIdx.x] = se;
        pn[tid * NBLK2 + blockIdx.x] = sh;
    }
}

// K2: merge 2048 per-block partials per disease with max-rescaling.
__global__ __launch_bounds__(256) void k_final(const float* __restrict__ pm,
                                               const float* __restrict__ pd,
                                               const float* __restrict__ pn,
                                               const float* __restrict__ temp_logit,
                                               const float* __restrict__ head_b,
                                               float* __restrict__ out) {
    const int d = blockIdx.x, tid = threadIdx.x;
    const int lane = tid & 63, wid = tid >> 6;
    __shared__ float sm[4], sd[4], sn[4];
    const float* bm = pm + d * NBLK2;
    const float* bd = pd + d * NBLK2;
    const float* bn = pn + d * NBLK2;

    float m[8], e[8], h[8];
#pragma unroll
    for (int i = 0; i < 8; i++) {
        int ix = tid + i * 256;
        m[i] = bm[ix]; e[i] = bd[ix]; h[i] = bn[ix];
    }
    float mx = m[0];
#pragma unroll
    for (int i = 1; i < 8; i++) mx = fmaxf(mx, m[i]);
#pragma unroll
    for (int off = 32; off > 0; off >>= 1) mx = fmaxf(mx, __shfl_xor(mx, off));
    if (lane == 0) sm[wid] = mx;
    __syncthreads();
    float M = fmaxf(fmaxf(sm[0], sm[1]), fmaxf(sm[2], sm[3]));

    float it = inv_tau(temp_logit[d]);
    float den = 0.f, num = 0.f;
#pragma unroll
    for (int i = 0; i < 8; i++) {
        float sc = expf((m[i] - M) * it);
        den += e[i] * sc;
        num += h[i] * sc;
    }
#pragma unroll
    for (int off = 32; off > 0; off >>= 1) {
        den += __shfl_xor(den, off);
        num += __shfl_xor(num, off);
    }
    if (lane == 0) { sd[wid] = den; sn[wid] = num; }
    __syncthreads();
    if (tid == 0) {
        float D = (sd[0] + sd[1]) + (sd[2] + sd[3]);
        float N = (sn[0] + sn[1]) + (sn[2] + sn[3]);
        float o = N / fmaxf(D, 1e-12f) + head_b[d];
        if (o != o) o = 0.f;
        out[d] = o;
    }
}

extern "C" void kernel_launch(void* const* d_in, const int* in_sizes, int n_in,
                              void* d_out, int out_size, void* d_ws, size_t ws_size,
                              hipStream_t stream) {
    const float* activ      = (const float*)d_in[0];
    const float* score_w    = (const float*)d_in[1];
    // d_in[2] = score_b — cancels exactly in the stable softmax, unused
    const float* head_w     = (const float*)d_in[3];
    const float* head_b     = (const float*)d_in[4];
    const float* temp_logit = (const float*)d_in[5];
    float* ws  = (float*)d_ws;
    float* out = (float*)d_out;

    short* afrag = (short*)ws;
    k_prep <<<576,   256, 0, stream>>>(score_w, head_w, afrag);
    k_mfma <<<NBLK2, 256, 0, stream>>>(activ, afrag, temp_logit,
                                       ws + PM_OFF, ws + PD_OFF, ws + PN_OFF);
    k_final<<<NDIS,  256, 0, stream>>>(ws + PM_OFF, ws + PD_OFF, ws + PN_OFF,
                                       temp_logit, head_b, out);
}

// Round 7
// 242.699 us; speedup vs baseline: 1.2465x; 1.0535x over previous
//
#include <hip/hip_runtime.h>

// ---------------- problem constants ----------------
#define CDIM 1152
#define NDIS 30
#define NVOX (64*64*64)        // 262144 voxels
#define NT   256               // voxels per block
#define NBLK3 (NVOX/NT)        // 1024 blocks
#define KSTEPS (CDIM/32)       // 36 K-steps of 32 channels
#define LROW 257               // padded LDS row stride (floats): bank-conflict-free B-reads

// ---------------- workspace layout (float offsets) ----------------
#define AF_FLOATS 73728
#define PM_OFF AF_FLOATS                    // [30][1024] per-block max of s
#define PD_OFF (PM_OFF + NDIS*NBLK3)        // [30][1024] per-block sum e
#define PN_OFF (PD_OFF + NDIS*NBLK3)        // [30][1024] per-block sum e*h

typedef float f32x4 __attribute__((ext_vector_type(4)));
typedef short bf16x8 __attribute__((ext_vector_type(8)));

__device__ inline short f2bf(float f) {
    unsigned u = __float_as_uint(f);
    unsigned r = (u + 0x7FFFu + ((u >> 16) & 1u)) >> 16;
    return (short)r;
}
__device__ inline float bf2f(short h) {
    return __uint_as_float(((unsigned)(unsigned short)h) << 16);
}
__device__ inline float inv_tau(float t) {
    float sig = 1.f / (1.f + expf(-t));
    return 1.f / (0.2f + 1.8f * sig);
}

// K0: precompute per-lane A-fragments (weights, bf16 hi/lo split).
// A-row m = lane&15 (0..29 score_w, 30..59 head_w, 60..63 zero); k = 8*(lane>>4)+e.
__global__ void k_prep(const float* __restrict__ score_w,
                       const float* __restrict__ head_w,
                       short* __restrict__ afrag) {
    int idx = blockIdx.x * 256 + threadIdx.x;      // 147456 total
    int e  = idx & 7;
    int l  = (idx >> 3) & 63;
    int p  = (idx >> 9) & 1;
    int mt = (idx >> 10) & 3;
    int t  = idx >> 12;
    if (t >= KSTEPS) return;
    int m = mt * 16 + (l & 15);
    int k = t * 32 + 8 * (l >> 4) + e;
    float w = 0.f;
    if (m < NDIS)          w = score_w[m * CDIM + k];
    else if (m < 2 * NDIS) w = head_w[(m - NDIS) * CDIM + k];
    short hi = f2bf(w);
    afrag[idx] = p ? f2bf(w - bf2f(hi)) : hi;
}

// K1 (hot): 512 threads / 8 waves, NT=256. Each global_load_lds covers one
// FULL 1KB-contiguous aligned row-slice (64 lanes x 16B) — doubles the DRAM
// fetch granularity vs the 512B x 2-row pattern (the round-7 A/B variable).
// Round-4-proven ordering: __syncthreads drain, then A(t) loads (L2),
// sched_barrier, stage(t+1) (HBM, stays in flight across compute), compute.
__global__ __launch_bounds__(512, 4) void k_mfma(const float* __restrict__ activ,
                                                 const short* __restrict__ afrag,
                                                 const float* __restrict__ temp_logit,
                                                 float* __restrict__ pm,
                                                 float* __restrict__ pd,
                                                 float* __restrict__ pn) {
    __shared__ float lds[2][32][LROW];        // 64.2 KB staging (padded rows)
    __shared__ float redm[32][16], rede[32][16], redh[32][16];

    const int tid  = threadIdx.x;
    const int lane = tid & 63;
    const int w    = tid >> 6;                // wave 0..7
    const int a    = lane >> 4;               // k-group 0..3
    const int i16  = lane & 15;
    const int nb   = blockIdx.x * NT;

    const bf16x8* afp = (const bf16x8*)afrag;

    f32x4 acc[4][2];
#pragma unroll
    for (int mt = 0; mt < 4; mt++)
#pragma unroll
        for (int nt = 0; nt < 2; nt++) acc[mt][nt] = (f32x4)0.f;

    // stage K-step t's [32][256] f32 tile into buffer b: wave w stages rows
    // 4w..4w+3, one 1KB-contiguous global_load_lds per row (lane offset 16B).
    auto stage = [&](int t, int b) {
#pragma unroll
        for (int q = 0; q < 4; q++) {
            const int row = 4 * w + q;                           // wave-uniform
            const float* g = activ + (size_t)(t * 32 + row) * NVOX + nb + lane * 4;
            __builtin_amdgcn_global_load_lds(
                (const __attribute__((address_space(1))) unsigned int*)g,
                (__attribute__((address_space(3))) unsigned int*)&lds[b][row][0],
                16, 0, 0);
        }
    };

    stage(0, 0);
#pragma unroll 1
    for (int t = 0; t < KSTEPS; t++) {
        const int b = t & 1;
        __syncthreads();                      // vmcnt(0)+barrier: buf b fully staged

        // A fragments first (L2-resident): their wait retires before the
        // stage(t+1) HBM loads issued below (in-order vmcnt).
        bf16x8 ah[4], al[4];
#pragma unroll
        for (int mt = 0; mt < 4; mt++) {
            ah[mt] = afp[(size_t)(t * 8 + mt * 2 + 0) * 64 + lane];
            al[mt] = afp[(size_t)(t * 8 + mt * 2 + 1) * 64 + lane];
        }
        __builtin_amdgcn_sched_barrier(0);    // pin: A-loads issue before stage(t+1)

        if (t + 1 < KSTEPS) stage(t + 1, 1 - b);   // in flight across compute

        // B fragments: padded stride makes these reads bank-conflict-free
        bf16x8 bh[2], bl[2];
#pragma unroll
        for (int nt = 0; nt < 2; nt++) {
            const int col = w * 32 + nt * 16 + i16;
#pragma unroll
            for (int e = 0; e < 8; e++) {
                float f = lds[b][8 * a + e][col];
                short hs = f2bf(f);                               // RTNE hi
                bh[nt][e] = hs;
                float lf = f - bf2f(hs);
                bl[nt][e] = (short)(__float_as_uint(lf) >> 16);   // trunc lo
            }
        }

        // 24 MFMA: (hi*hi + hi*lo + lo*hi)
#pragma unroll
        for (int mt = 0; mt < 4; mt++)
#pragma unroll
            for (int nt = 0; nt < 2; nt++) {
                acc[mt][nt] = __builtin_amdgcn_mfma_f32_16x16x32_bf16(ah[mt], bh[nt], acc[mt][nt], 0, 0, 0);
                acc[mt][nt] = __builtin_amdgcn_mfma_f32_16x16x32_bf16(ah[mt], bl[nt], acc[mt][nt], 0, 0, 0);
                acc[mt][nt] = __builtin_amdgcn_mfma_f32_16x16x32_bf16(al[mt], bh[nt], acc[mt][nt], 0, 0, 0);
            }
    }

    // ---- epilogue: dump D[64][256] to LDS (stride LROW), softmax partials ----
    __syncthreads();                          // everyone done reading staging LDS
    float* epf = &lds[0][0][0];               // 64 rows x LROW overlay (fits exactly)
#pragma unroll
    for (int mt = 0; mt < 4; mt++)
#pragma unroll
        for (int nt = 0; nt < 2; nt++)
#pragma unroll
            for (int r = 0; r < 4; r++) {
                int m = mt * 16 + a * 4 + r;  // verified C/D map: row=(lane>>4)*4+reg
                int n = w * 32 + nt * 16 + i16;
                epf[m * LROW + n] = acc[mt][nt][r];
            }
    __syncthreads();

    const int d   = tid >> 4;                 // 0..31 (30 used)
    const int j16 = tid & 15;                 // 16 threads per disease
    if (d < NDIS) {
        float mx = -3.4e38f;
        for (int i = 0; i < 16; i++) mx = fmaxf(mx, epf[d * LROW + j16 * 16 + i]);
        redm[d][j16] = mx;
    }
    __syncthreads();
    if (d < NDIS) {
        float mb = redm[d][0];
        for (int j = 1; j < 16; j++) mb = fmaxf(mb, redm[d][j]);
        float it = inv_tau(temp_logit[d]);
        float se = 0.f, sh = 0.f;
        for (int i = 0; i < 16; i++) {
            float e = expf((epf[d * LROW + j16 * 16 + i] - mb) * it);
            se += e;
            sh += e * epf[(d + NDIS) * LROW + j16 * 16 + i];
        }
        rede[d][j16] = se;
        redh[d][j16] = sh;
    }
    __syncthreads();
    if (tid < NDIS) {
        float mb = redm[tid][0];
        for (int j = 1; j < 16; j++) mb = fmaxf(mb, redm[tid][j]);
        float se = 0.f, sh = 0.f;
        for (int j = 0; j < 16; j++) { se += rede[tid][j]; sh += redh[tid][j]; }
        pm[tid * NBLK3 + blockIdx.x] = mb;
        pd[tid * NBLK3 + blockIdx.x] = se;
        pn[tid * NBLK3 + blockIdx.x] = sh;
    }
}

// K2: merge 1024 per-block partials per disease with max-rescaling.
__global__ __launch_bounds__(256) void k_final(const float* __restrict__ pm,
                                               const float* __restrict__ pd,
                                               const float* __restrict__ pn,
                                               const float* __restrict__ temp_logit,
                                               const float* __restrict__ head_b,
                                               float* __restrict__ out) {
    const int d = blockIdx.x, tid = threadIdx.x;
    const int lane = tid & 63, wid = tid >> 6;
    __shared__ float sm[4], sd[4], sn[4];
    const float* bm = pm + d * NBLK3;
    const float* bd = pd + d * NBLK3;
    const float* bn = pn + d * NBLK3;

    float m[4], e[4], h[4];
#pragma unroll
    for (int i = 0; i < 4; i++) {
        int ix = tid + i * 256;
        m[i] = bm[ix]; e[i] = bd[ix]; h[i] = bn[ix];
    }
    float mx = m[0];
#pragma unroll
    for (int i = 1; i < 4; i++) mx = fmaxf(mx, m[i]);
#pragma unroll
    for (int off = 32; off > 0; off >>= 1) mx = fmaxf(mx, __shfl_xor(mx, off));
    if (lane == 0) sm[wid] = mx;
    __syncthreads();
    float M = fmaxf(fmaxf(sm[0], sm[1]), fmaxf(sm[2], sm[3]));

    float it = inv_tau(temp_logit[d]);
    float den = 0.f, num = 0.f;
#pragma unroll
    for (int i = 0; i < 4; i++) {
        float sc = expf((m[i] - M) * it);
        den += e[i] * sc;
        num += h[i] * sc;
    }
#pragma unroll
    for (int off = 32; off > 0; off >>= 1) {
        den += __shfl_xor(den, off);
        num += __shfl_xor(num, off);
    }
    if (lane == 0) { sd[wid] = den; sn[wid] = num; }
    __syncthreads();
    if (tid == 0) {
        float D = (sd[0] + sd[1]) + (sd[2] + sd[3]);
        float N = (sn[0] + sn[1]) + (sn[2] + sn[3]);
        float o = N / fmaxf(D, 1e-12f) + head_b[d];
        if (o != o) o = 0.f;
        out[d] = o;
    }
}

extern "C" void kernel_launch(void* const* d_in, const int* in_sizes, int n_in,
                              void* d_out, int out_size, void* d_ws, size_t ws_size,
                              hipStream_t stream) {
    const float* activ      = (const float*)d_in[0];
    const float* score_w    = (const float*)d_in[1];
    // d_in[2] = score_b — cancels exactly in the stable softmax, unused
    const float* head_w     = (const float*)d_in[3];
    const float* head_b     = (const float*)d_in[4];
    const float* temp_logit = (const float*)d_in[5];
    float* ws  = (float*)d_ws;
    float* out = (float*)d_out;

    short* afrag = (short*)ws;
    k_prep <<<576,   256, 0, stream>>>(score_w, head_w, afrag);
    k_mfma <<<NBLK3, 512, 0, stream>>>(activ, afrag, temp_logit,
                                       ws + PM_OFF, ws + PD_OFF, ws + PN_OFF);
    k_final<<<NDIS,  256, 0, stream>>>(ws + PM_OFF, ws + PD_OFF, ws + PN_OFF,
                                       temp_logit, head_b, out);
}